// Round 6
// baseline (493.882 us; speedup 1.0000x reference)
//
#include <hip/hip_runtime.h>
#include <hip/hip_bf16.h>
#include <stdint.h>

// Problem: out[b,s,o] = alpha * sum_k x[b,s,k] * t[o,k],  t in {-1,0,+1}
// M = 4*2048 = 8192, K = 4096, N = 4096.
#define M_DIM 8192
#define K_DIM 4096
#define N_DIM 4096

typedef __attribute__((ext_vector_type(8))) short short8;
typedef __attribute__((ext_vector_type(4))) float f32x4;

// ---------------------------------------------------------------------------
// async global->LDS, 16B per lane (global_load_lds_dwordx4)
// ---------------------------------------------------------------------------
__device__ __forceinline__ void lds_load16(const ushort* g, ushort* l) {
    __builtin_amdgcn_global_load_lds(
        (const __attribute__((address_space(1))) uint32_t*)g,
        (__attribute__((address_space(3))) uint32_t*)l, 16, 0, 0);
}

__device__ __forceinline__ ushort f2bf_rne(float f) {
    uint32_t u = __float_as_uint(f);
    uint32_t r = (u + 0x7FFFu + ((u >> 16) & 1u)) >> 16;
    return (ushort)r;
}

// ---------------------------------------------------------------------------
// Pass 1 (fused): per-block partial sums of |w| (fp64, deterministic)
//                 + cast x fp32 -> bf16.  Grid-stride, 2048 blocks.
// ---------------------------------------------------------------------------
__global__ void k_prep(const float* __restrict__ w, double* __restrict__ partial,
                       const float* __restrict__ x, ushort* __restrict__ xb) {
    const int nth = gridDim.x * blockDim.x;
    const int gtid = blockIdx.x * blockDim.x + threadIdx.x;

    const float4* w4 = (const float4*)w;
    double s = 0.0;
    for (int i = gtid; i < (K_DIM * N_DIM) / 4; i += nth) {
        float4 v = w4[i];
        s += (double)fabsf(v.x) + (double)fabsf(v.y) + (double)fabsf(v.z) + (double)fabsf(v.w);
    }
    #pragma unroll
    for (int off = 32; off > 0; off >>= 1) s += __shfl_down(s, off, 64);
    __shared__ double sm[4];
    int lane = threadIdx.x & 63, wv = threadIdx.x >> 6;
    if (lane == 0) sm[wv] = s;
    __syncthreads();
    if (threadIdx.x == 0) partial[blockIdx.x] = sm[0] + sm[1] + sm[2] + sm[3];

    const f32x4* x4 = (const f32x4*)x;
    ushort4* xb4 = (ushort4*)xb;
    for (int i = gtid; i < (M_DIM * K_DIM) / 4; i += nth) {
        f32x4 v = __builtin_nontemporal_load(&x4[i]);   // read-once stream
        ushort4 o;
        o.x = f2bf_rne(v[0]);
        o.y = f2bf_rne(v[1]);
        o.z = f2bf_rne(v[2]);
        o.w = f2bf_rne(v[3]);
        xb4[i] = o;   // normal store: want xb L3-resident for the GEMM
    }
}

// Pass 1b: finalize alpha = mean(|w|) over 2048 partials
__global__ void k_alpha(const double* __restrict__ partial, float* __restrict__ alpha_out) {
    double s = 0.0;
    for (int i = threadIdx.x; i < 2048; i += 256) s += partial[i];
    #pragma unroll
    for (int off = 32; off > 0; off >>= 1) s += __shfl_down(s, off, 64);
    __shared__ double sm[4];
    int lane = threadIdx.x & 63, wv = threadIdx.x >> 6;
    if (lane == 0) sm[wv] = s;
    __syncthreads();
    if (threadIdx.x == 0) {
        double total = sm[0] + sm[1] + sm[2] + sm[3];
        alpha_out[0] = (float)(total * (1.0 / 16777216.0));
    }
}

// ---------------------------------------------------------------------------
// Pass 2: quantize w -> ternary {-1,0,+1} as bf16 (N x K row-major)
// ---------------------------------------------------------------------------
__global__ void k_quant(const float* __restrict__ w, const float* __restrict__ alpha_p,
                        ushort* __restrict__ qw) {
    const float thr = 0.5f * alpha_p[0];
    const int nth = gridDim.x * blockDim.x;
    const int gtid = blockIdx.x * blockDim.x + threadIdx.x;
    const float4* w4 = (const float4*)w;
    short8* q8 = (short8*)qw;
    for (int i = gtid; i < (K_DIM * N_DIM) / 8; i += nth) {
        float4 a = w4[2 * i], b = w4[2 * i + 1];
        short8 o;
        o[0] = a.x > thr ? (short)0x3F80 : (a.x < -thr ? (short)0xBF80 : (short)0);
        o[1] = a.y > thr ? (short)0x3F80 : (a.y < -thr ? (short)0xBF80 : (short)0);
        o[2] = a.z > thr ? (short)0x3F80 : (a.z < -thr ? (short)0xBF80 : (short)0);
        o[3] = a.w > thr ? (short)0x3F80 : (a.w < -thr ? (short)0xBF80 : (short)0);
        o[4] = b.x > thr ? (short)0x3F80 : (b.x < -thr ? (short)0xBF80 : (short)0);
        o[5] = b.y > thr ? (short)0x3F80 : (b.y < -thr ? (short)0xBF80 : (short)0);
        o[6] = b.z > thr ? (short)0x3F80 : (b.z < -thr ? (short)0xBF80 : (short)0);
        o[7] = b.w > thr ? (short)0x3F80 : (b.w < -thr ? (short)0xBF80 : (short)0);
        q8[i] = o;
    }
}

// ---------------------------------------------------------------------------
// Pass 3: 256x256 bf16 MFMA GEMM — BK=32, QUAD-buffered LDS, counted vmcnt.
//   512 threads = 8 waves (2M x 4N), per-wave C = 128x64 (acc 128 AGPR).
//   LDS: 4 buffers x 32KB (A 256x32 + B 256x32 bf16), buffer = (t & 3).
//   Swizzle (64B rows, 4x16B chunks): stored slot = chunk ^ ((row>>1)&3),
//   applied on pre-swizzled gload SOURCE and on ds_read addr (both-sides,
//   rule 21). Wave b128 reads: 8 lanes per 4-bank group, even => conflict-free.
//   Pipeline: staging distance +3 tiles; per tile: stage(t+3) -> counted
//   s_waitcnt vmcnt(8) (drains ONLY tile t+1, keeps t+2/t+3 in flight; tail
//   8->4->0) -> barrier -> 32 MFMA(t) with am[i] reload (t+1) interleaved
//   after each frag's last use, b reload after cluster -> barrier.
//   NO full vmcnt(0) drain in the main loop (the round-4/5 schedules paid a
//   full drain every tile under a ~2TB/s-congested memory system).
//   Hazards: stage(t+3) overwrites buf[(t-1)&3]; its readers (reloads issued
//   in tile t-2) drained at their pre-MFMA(t-1) lgkm waits, and all waves
//   passed the t-1-end barrier before any stage(t+3) issues. 2 barriers/tile.
// ---------------------------------------------------------------------------
#define NT (K_DIM / 32)  // 128 K-tiles

#define MFMA16(a, b, c) __builtin_amdgcn_mfma_f32_16x16x32_bf16((a), (b), (c), 0, 0, 0)

__global__ __launch_bounds__(512, 2) void k_gemm(const ushort* __restrict__ A,  // M x K bf16
                                                 const ushort* __restrict__ B,  // N x K bf16
                                                 const float* __restrict__ alpha_p,
                                                 float* __restrict__ C) {
    // 128 KiB LDS: buf*16384 + {A:0 | B:8192} + row*32 + slot*8 (ushorts)
    __shared__ __align__(16) ushort lds[65536];

    const int tid = threadIdx.x;
    const int lane = tid & 63;
    const int w = tid >> 6;       // 0..7
    const int wr = w >> 2;        // 0..1  M wave-group
    const int wc = w & 3;         // 0..3  N wave-group
    const int r = lane & 15, q = lane >> 4;

    // T1: XCD-aware bijective swizzle (512 blocks, 512 % 8 == 0)
    const int wg = blockIdx.x;
    const int swz = (wg & 7) * 64 + (wg >> 3);
    const int bm = swz >> 4;      // 0..31 (M tiles)
    const int bn = swz & 15;      // 0..15 (N tiles)

    float alpha = alpha_p[0];
    asm volatile("" :: "v"(alpha));

    const ushort* Abase = A + (size_t)bm * 256 * K_DIM;
    const ushort* Bbase = B + (size_t)bn * 256 * K_DIM;

    // staging: one gload pt = 512 threads x 16B = 8KB = 128 rows of 64B.
    // thread covers (row-in-pt = tid>>2, slot = tid&3); stored logical chunk
    // = slot ^ ((row>>1)&3) = (tid&3) ^ ((tid>>3)&3)  [pre-swizzled source].
    const int srow = tid >> 2;
    const int sch = (tid & 3) ^ ((tid >> 3) & 3);

    // read: frag (row = base16 + r, chunk q) lives at slot q ^ ((r>>1)&3)
    // (base16 is a multiple of 16 => (row>>1)&3 == (r>>1)&3).
    const int oA = r * 32 + (q ^ ((r >> 1) & 3)) * 8;

    const int aoff = wr * 4096;           // wave's A base (rows wr*128..)
    const int boff = 8192 + wc * 2048;    // wave's B base (cols wc*64..)

    f32x4 acc[8][4] = {};   // [m-frag 0..7][n-frag 0..3]
    short8 am[8], bf[4];

    auto SA = [&](int p, int bb, int tt) {
        const ushort* g = Abase + (size_t)(p * 128 + srow) * K_DIM + tt * 32 + sch * 8;
        lds_load16(g, lds + bb * 16384 + p * 4096 + tid * 8);
    };
    auto SB = [&](int p, int bb, int tt) {
        const ushort* g = Bbase + (size_t)(p * 128 + srow) * K_DIM + tt * 32 + sch * 8;
        lds_load16(g, lds + bb * 16384 + 8192 + p * 4096 + tid * 8);
    };
    auto STAGE = [&](int tt) {   // 4 gload instrs/thread per tile
        const int bb = tt & 3;
        SA(0, bb, tt); SA(1, bb, tt); SB(0, bb, tt); SB(1, bb, tt);
    };

    // ---- prologue: stage t0,t1,t2 (12 instrs); drain t0 only; read frags(t0)
    STAGE(0); STAGE(1); STAGE(2);
    asm volatile("s_waitcnt vmcnt(8)" ::: "memory");
    __builtin_amdgcn_s_barrier();
    {
        const ushort* aP = lds + aoff;
        const ushort* bP = lds + boff;
        #pragma unroll
        for (int i = 0; i < 8; ++i) am[i] = *(const short8*)(aP + i * 512 + oA);
        #pragma unroll
        for (int j = 0; j < 4; ++j) bf[j] = *(const short8*)(bP + j * 512 + oA);
    }

    for (int t = 0; t < NT - 1; ++t) {
        if (t + 3 < NT) STAGE(t + 3);
        // counted drain: leave tiles >t+1 in flight, drain exactly t+1
        if (t + 3 < NT)      asm volatile("s_waitcnt vmcnt(8)" ::: "memory");
        else if (t + 2 < NT) asm volatile("s_waitcnt vmcnt(4)" ::: "memory");
        else                 asm volatile("s_waitcnt vmcnt(0)" ::: "memory");
        __builtin_amdgcn_s_barrier();

        const ushort* aN = lds + ((t + 1) & 3) * 16384 + aoff;
        const ushort* bN = lds + ((t + 1) & 3) * 16384 + boff;

        __builtin_amdgcn_s_setprio(1);
        #pragma unroll
        for (int i = 0; i < 8; ++i) {
            acc[i][0] = MFMA16(am[i], bf[0], acc[i][0]);
            acc[i][1] = MFMA16(am[i], bf[1], acc[i][1]);
            acc[i][2] = MFMA16(am[i], bf[2], acc[i][2]);
            acc[i][3] = MFMA16(am[i], bf[3], acc[i][3]);
            // reload this frag for t+1 (after its last use; WAR keeps order)
            am[i] = *(const short8*)(aN + i * 512 + oA);
        }
        __builtin_amdgcn_s_setprio(0);
        #pragma unroll
        for (int j = 0; j < 4; ++j) bf[j] = *(const short8*)(bN + j * 512 + oA);
        __builtin_amdgcn_s_barrier();
    }

    // ---- final tile: MFMA only (all staging drained at t=NT-2's vmcnt(0))
    __builtin_amdgcn_s_setprio(1);
    #pragma unroll
    for (int i = 0; i < 8; ++i) {
        acc[i][0] = MFMA16(am[i], bf[0], acc[i][0]);
        acc[i][1] = MFMA16(am[i], bf[1], acc[i][1]);
        acc[i][2] = MFMA16(am[i], bf[2], acc[i][2]);
        acc[i][3] = MFMA16(am[i], bf[3], acc[i][3]);
    }
    __builtin_amdgcn_s_setprio(0);

    // ---- epilogue: C/D layout col = lane&15, row = (lane>>4)*4 + reg  [m89]
    // nt stores: C is write-once; keep it out of L2/L3 (round-5 win).
    const int row0 = bm * 256 + wr * 128 + q * 4;
    const int col0 = bn * 256 + wc * 64 + r;
    #pragma unroll
    for (int i = 0; i < 8; ++i)
        #pragma unroll
        for (int j = 0; j < 4; ++j)
            #pragma unroll
            for (int v = 0; v < 4; ++v)
                __builtin_nontemporal_store(
                    alpha * acc[i][j][v],
                    &C[(size_t)(row0 + i * 16 + v) * N_DIM + col0 + j * 16]);
}

// ---------------------------------------------------------------------------
extern "C" void kernel_launch(void* const* d_in, const int* in_sizes, int n_in,
                              void* d_out, int out_size, void* d_ws, size_t ws_size,
                              hipStream_t stream) {
    const float* x = (const float*)d_in[0];  // 4*2048*4096 fp32
    const float* w = (const float*)d_in[1];  // 4096*4096 fp32
    float* out = (float*)d_out;              // 8192*4096 fp32

    char* ws = (char*)d_ws;
    double* partial = (double*)ws;                           // 16 KB (2048 doubles)
    float* alpha = (float*)(ws + 16384);                     // 4 B
    ushort* qw = (ushort*)(ws + 32768);                      // 32 MB (N x K bf16 ternary)
    ushort* xb = (ushort*)(ws + 32768 + (size_t)K_DIM * N_DIM * 2);  // 64 MB (M x K bf16)

    k_prep<<<2048, 256, 0, stream>>>(w, partial, x, xb);
    k_alpha<<<1, 256, 0, stream>>>(partial, alpha);
    k_quant<<<2048, 256, 0, stream>>>(w, alpha, qw);

    // 256x256 tiles: (8192/256)*(4096/256) = 32*16 = 512 blocks of 512 threads
    k_gemm<<<512, 512, 0, stream>>>(xb, qw, alpha, out);
}